// Round 3
// baseline (5988.599 us; speedup 1.0000x reference)
//
#include <hip/hip_runtime.h>
#include <stdint.h>

typedef unsigned short ushortT;
typedef __attribute__((ext_vector_type(8))) short short8;
typedef __attribute__((ext_vector_type(4))) float f32x4;

#define B_ 128
#define T_ 512
#define I_ 512
#define H_ 512
#define NG 1536     // 3*512 gate cols
#define NTOT 1544   // + 8 q cols

__device__ __forceinline__ float bf2f(ushortT u){
  union { unsigned int i; float f; } v; v.i = ((unsigned int)u) << 16; return v.f;
}
__device__ __forceinline__ ushortT f2bf(float f){           // RNE
  union { float f; unsigned int i; } v; v.f = f;
  unsigned int u = v.i;
  u += 0x7fffu + ((u >> 16) & 1u);
  return (ushortT)(u >> 16);
}
// truncating split: x == hi + lo to ~17 mantissa bits
__device__ __forceinline__ void splitf(float x, ushortT& hi, ushortT& lo){
  union { float f; unsigned int i; } v; v.f = x;
  hi = (ushortT)(v.i >> 16);
  union { unsigned int i; float f; } h; h.i = v.i & 0xffff0000u;
  union { float f; unsigned int i; } r; r.f = x - h.f;
  lo = (ushortT)(r.i >> 16);
}
__device__ __forceinline__ float sigf(float x){ return 1.f / (1.f + __expf(-x)); }
__device__ __forceinline__ float tanhfast(float x){
  float e = __expf(-2.f * fabsf(x));
  float t = (1.f - e) / (1.f + e);
  return copysignf(t, x);
}
__device__ __forceinline__ void stx(float* p, size_t i, float v){ p[i] = v; }
__device__ __forceinline__ void stx(ushortT* p, size_t i, float v){ p[i] = f2bf(v); }
__device__ __forceinline__ float ldx(const float* p, size_t i){ return p[i]; }
__device__ __forceinline__ float ldx(const ushortT* p, size_t i){ return bf2f(p[i]); }

// ---------------------------------------------------------------------------
// Kernel A: weight prep (fp32 in). btx[n][k] = bf16(W*(k,n));
// bth_hi/lo[n][k] = hi/lo split of W*(512+k,n). n in [0,1544) = [Wi|Wg|Wo|Wf].
// ---------------------------------------------------------------------------
__global__ __launch_bounds__(256) void prep_w(
    const float* __restrict__ Wi, const float* __restrict__ Wg,
    const float* __restrict__ Wo, const float* __restrict__ Wf,
    ushortT* __restrict__ btx, ushortT* __restrict__ bth_hi,
    ushortT* __restrict__ bth_lo, int wlo)
{
  int e = blockIdx.x * 256 + threadIdx.x;   // 1544*512 = 3088*256
  int n = e >> 9;
  int k = e & 511;
  const float* W; int ld, c;
  if (n < 512){ W = Wi; ld = 512; c = n; }
  else if (n < 1024){ W = Wg; ld = 512; c = n - 512; }
  else if (n < 1536){ W = Wo; ld = 512; c = n - 1024; }
  else { W = Wf; ld = 8; c = n - 1536; }
  btx[e] = f2bf(W[(size_t)k * ld + c]);
  float wh = W[(size_t)(512 + k) * ld + c];
  ushortT hi, lo; splitf(wh, hi, lo);
  bth_hi[e] = hi;
  if (wlo) bth_lo[e] = lo;
}

// ---------------------------------------------------------------------------
// Kernel B: xproj[r][n] = bf16(x_flat[r][:]) @ btx^T + bias, r = b*T+t.
// Gate cols -> xp (XPT, stride XPST); q cols -> qx fp32 (if QX32) else xp.
// ---------------------------------------------------------------------------
template<typename XPT, bool QX32, int XPST>
__global__ __launch_bounds__(256) void xproj_gemm(
    const float* __restrict__ x, const ushortT* __restrict__ btx,
    const float* __restrict__ bi, const float* __restrict__ bg,
    const float* __restrict__ bo, const float* __restrict__ bfv,
    XPT* __restrict__ xp, float* __restrict__ qx)
{
  __shared__ ushortT As[128][72];   // +8 pad
  __shared__ ushortT Bs[128][72];
  const int tid = threadIdx.x;
  const int n0 = blockIdx.x * 128;
  const int m0 = blockIdx.y * 128;
  const int wid = tid >> 6, lane = tid & 63;
  const int nn = lane & 15, quad = lane >> 4;

  f32x4 acc[2][8];
  #pragma unroll
  for (int a = 0; a < 2; ++a)
    #pragma unroll
    for (int b = 0; b < 8; ++b) acc[a][b] = (f32x4){0.f,0.f,0.f,0.f};

  for (int kb = 0; kb < 8; ++kb){
    #pragma unroll
    for (int u = 0; u < 4; ++u){
      int idx = u*256 + tid;
      int r = idx >> 3, k8 = (idx & 7) * 8;
      const float* xa = &x[(size_t)(m0 + r) * I_ + kb*64 + k8];
      f32x4 f0 = *(const f32x4*)xa;
      f32x4 f1 = *(const f32x4*)(xa + 4);
      short8 av;
      #pragma unroll
      for (int i = 0; i < 4; ++i){ av[i] = (short)f2bf(f0[i]); av[4+i] = (short)f2bf(f1[i]); }
      *(short8*)&As[r][k8] = av;
      int ng = n0 + r;
      short8 bv = {0,0,0,0,0,0,0,0};
      if (ng < NTOT)
        bv = *(const short8*)&btx[(size_t)ng * 512 + kb*64 + k8];
      *(short8*)&Bs[r][k8] = bv;
    }
    __syncthreads();
    #pragma unroll
    for (int kc = 0; kc < 2; ++kc){
      int ko = kc*32 + quad*8;
      short8 a0 = *(const short8*)&As[wid*32 + nn][ko];
      short8 a1 = *(const short8*)&As[wid*32 + 16 + nn][ko];
      #pragma unroll
      for (int nt = 0; nt < 8; ++nt){
        short8 b = *(const short8*)&Bs[nt*16 + nn][ko];
        acc[0][nt] = __builtin_amdgcn_mfma_f32_16x16x32_bf16(a0, b, acc[0][nt], 0,0,0);
        acc[1][nt] = __builtin_amdgcn_mfma_f32_16x16x32_bf16(a1, b, acc[1][nt], 0,0,0);
      }
    }
    __syncthreads();
  }
  #pragma unroll
  for (int nt = 0; nt < 8; ++nt){
    int c = n0 + nt*16 + nn;
    if (c >= NTOT) continue;
    float bias;
    if (c < 512) bias = bi[c];
    else if (c < 1024) bias = bg[c - 512];
    else if (c < NG) bias = bo[c - 1024];
    else bias = bfv[c - NG];
    #pragma unroll
    for (int mt = 0; mt < 2; ++mt){
      int rb = m0 + wid*32 + mt*16 + quad*4;
      #pragma unroll
      for (int r = 0; r < 4; ++r){
        float v = acc[mt][nt][r] + bias;
        if (c < NG)
          stx(xp, (size_t)(rb + r) * XPST + c, v);
        else if (QX32)
          qx[(size_t)(rb + r) * 8 + (c - NG)] = v;
        else
          stx(xp, (size_t)(rb + r) * XPST + c, v);
      }
    }
  }
}

// ---------------------------------------------------------------------------
// Kernel C: ONE timestep. 256 blocks: g = blk&7 (16 batch rows), s = blk>>3
// (16 H cols). Waves 0..2: i/g/o; wave 3: q. A = fp32 h(t-1) split to
// bf16 hi/lo on the fly; B = pre-split weights; 3-product MFMA (if WLO).
// ---------------------------------------------------------------------------
template<typename XPT, bool QX32, bool WLO, int XPST>
__global__ __launch_bounds__(256) void qlstm_step(
    float* __restrict__ dout, const float* __restrict__ h0,
    const float* __restrict__ c0, float* __restrict__ cbuf,
    const ushortT* __restrict__ bth_hi, const ushortT* __restrict__ bth_lo,
    const XPT* __restrict__ xp, const float* __restrict__ qx,
    const float* __restrict__ Wfp, const float* __restrict__ bfp,
    const float* __restrict__ qa, const float* __restrict__ qbv,
    const float* __restrict__ qpar, int t)
{
  __shared__ float sGb[3][16][16];
  __shared__ float sQbuf[16][8];

  const int tid = threadIdx.x;
  const int g = blockIdx.x & 7, s = blockIdx.x >> 3;
  const int b0 = g * 16, j0 = s * 16;
  const int wid = tid >> 6, lane = tid & 63;
  const int nn = lane & 15, quad = lane >> 4;

  const int wrow = (wid < 3) ? (wid*512 + j0 + nn) : (NG + (nn & 7));
  const bool colok = (wid < 3) || (nn < 8);

  const float* arow = (t == 0)
      ? (h0 + (size_t)(b0 + nn) * H_)
      : (dout + ((size_t)(b0 + nn) * T_ + (t - 1)) * H_);
  const ushortT* bhrow = bth_hi + (size_t)wrow * 512;
  const ushortT* blrow = bth_lo + (size_t)wrow * 512;

  float xpv[4];
  #pragma unroll
  for (int r = 0; r < 4; ++r){
    int b = quad*4 + r;
    if (!colok){ xpv[r] = 0.f; continue; }
    if (wid < 3)
      xpv[r] = ldx(xp, ((size_t)(b0 + b) * T_ + t) * XPST + wrow);
    else if (QX32)
      xpv[r] = qx[((size_t)(b0 + b) * T_ + t) * 8 + nn];
    else
      xpv[r] = ldx(xp, ((size_t)(b0 + b) * T_ + t) * XPST + NG + nn);
  }

  f32x4 acc = {0.f,0.f,0.f,0.f};
  #pragma unroll
  for (int kc = 0; kc < 16; ++kc){
    const float* ar = arow + kc*32 + quad*8;
    f32x4 h0v = *(const f32x4*)ar;
    f32x4 h1v = *(const f32x4*)(ar + 4);
    short8 ahi, alo;
    #pragma unroll
    for (int i = 0; i < 4; ++i){
      ushortT hi, lo;
      splitf(h0v[i], hi, lo); ahi[i] = (short)hi; alo[i] = (short)lo;
      splitf(h1v[i], hi, lo); ahi[4+i] = (short)hi; alo[4+i] = (short)lo;
    }
    short8 bhi = *(const short8*)&bhrow[kc*32 + quad*8];
    if (WLO){
      short8 blo = *(const short8*)&blrow[kc*32 + quad*8];
      acc = __builtin_amdgcn_mfma_f32_16x16x32_bf16(alo, bhi, acc, 0,0,0);
      acc = __builtin_amdgcn_mfma_f32_16x16x32_bf16(ahi, blo, acc, 0,0,0);
    }
    acc = __builtin_amdgcn_mfma_f32_16x16x32_bf16(ahi, bhi, acc, 0,0,0);
  }

  if (wid < 3){
    #pragma unroll
    for (int r = 0; r < 4; ++r){
      float v = acc[r] + xpv[r];
      v = (wid == 1) ? tanhfast(v) : sigf(v);
      sGb[wid][quad*4 + r][nn] = v;
    }
  } else if (nn < 8){
    float a0 = qa[0], a1 = qa[1], a2 = qa[2];
    float n0v = qbv[0], n1 = qbv[1], n2 = qbv[2];
    float qp = qpar[nn];
    #pragma unroll
    for (int r = 0; r < 4; ++r){
      float v = acc[r] + xpv[r];
      v = tanhfast(v * a0 + n0v);
      v = tanhfast(v * a1 + n1);
      v = tanhfast(v * a2 + n2);
      sQbuf[quad*4 + r][nn] = v + qp;
    }
  }
  __syncthreads();

  const int eb = tid >> 4, ej = tid & 15;
  const int jg = j0 + ej;
  float fpre = bfp[jg];
  #pragma unroll
  for (int nq = 0; nq < 8; ++nq)
    fpre += sQbuf[eb][nq] * Wfp[nq*512 + jg];
  float f = sigf(fpre);
  float iv = sGb[0][eb][ej], gv = sGb[1][eb][ej], ov = sGb[2][eb][ej];
  size_t ci = (size_t)(b0 + eb) * H_ + jg;
  float c = (t == 0) ? c0[ci] : cbuf[ci];
  c = f * c + iv * gv;
  cbuf[ci] = c;
  dout[((size_t)(b0 + eb) * T_ + t) * H_ + jg] = ov * tanhfast(c);
}

// ---------------------------------------------------------------------------
extern "C" void kernel_launch(void* const* d_in, const int* in_sizes, int n_in,
                              void* d_out, int out_size, void* d_ws, size_t ws_size,
                              hipStream_t stream)
{
  const float* x   = (const float*)d_in[0];
  const float* h0  = (const float*)d_in[1];
  const float* c0  = (const float*)d_in[2];
  const float* Wi  = (const float*)d_in[3];
  const float* bi  = (const float*)d_in[4];
  const float* Wg  = (const float*)d_in[5];
  const float* bg  = (const float*)d_in[6];
  const float* Wo  = (const float*)d_in[7];
  const float* bo  = (const float*)d_in[8];
  const float* Wf  = (const float*)d_in[9];
  const float* bfv = (const float*)d_in[10];
  const float* qa  = (const float*)d_in[11];
  const float* qb  = (const float*)d_in[12];
  const float* qp  = (const float*)d_in[13];
  const float* Wfp = (const float*)d_in[14];
  const float* bfp = (const float*)d_in[15];
  float* outp = (float*)d_out;

  const size_t R    = 65536;                         // B*T rows
  const size_t WB   = (size_t)NTOT * 512 * 2;        // one bf16 weight block: 1,581,056 B
  const size_t QXB  = R * 8 * 4;                     // 2,097,152 B
  const size_t CB   = (size_t)B_ * H_ * 4;           // 262,144 B
  const size_t XP32 = R * NG * 4;                    // 402,653,184 B
  const size_t XP16 = R * NG * 2;                    // 201,326,592 B
  const size_t XPF  = R * NTOT * 2;                  // 202,375,168 B (tier 3, q inline)

  const size_t t1 = XP32 + QXB + 3*WB + CB;          // ~390.7 MiB
  const size_t t2 = XP16 + QXB + 3*WB + CB;          // ~198.8 MiB
  const size_t t3 = XPF + 2*WB;                      // ~196.0 MiB (cbuf overlaps btx)

  char* ws = (char*)d_ws;

  if (ws_size >= t1){
    float*   xp     = (float*)ws;
    float*   qx     = (float*)(ws + XP32);
    ushortT* btx    = (ushortT*)(ws + XP32 + QXB);
    ushortT* bth_hi = (ushortT*)(ws + XP32 + QXB + WB);
    ushortT* bth_lo = (ushortT*)(ws + XP32 + QXB + 2*WB);
    float*   cbuf   = (float*)(ws + XP32 + QXB + 3*WB);
    prep_w<<<dim3(3088), dim3(256), 0, stream>>>(Wi, Wg, Wo, Wf, btx, bth_hi, bth_lo, 1);
    xproj_gemm<float, true, NG><<<dim3(13, 512), dim3(256), 0, stream>>>(
        x, btx, bi, bg, bo, bfv, xp, qx);
    for (int t = 0; t < T_; ++t)
      qlstm_step<float, true, true, NG><<<dim3(256), dim3(256), 0, stream>>>(
          outp, h0, c0, cbuf, bth_hi, bth_lo, xp, qx, Wfp, bfp, qa, qb, qp, t);
  } else if (ws_size >= t2){
    ushortT* xp     = (ushortT*)ws;
    float*   qx     = (float*)(ws + XP16);
    ushortT* btx    = (ushortT*)(ws + XP16 + QXB);
    ushortT* bth_hi = (ushortT*)(ws + XP16 + QXB + WB);
    ushortT* bth_lo = (ushortT*)(ws + XP16 + QXB + 2*WB);
    float*   cbuf   = (float*)(ws + XP16 + QXB + 3*WB);
    prep_w<<<dim3(3088), dim3(256), 0, stream>>>(Wi, Wg, Wo, Wf, btx, bth_hi, bth_lo, 1);
    xproj_gemm<ushortT, true, NG><<<dim3(13, 512), dim3(256), 0, stream>>>(
        x, btx, bi, bg, bo, bfv, xp, qx);
    for (int t = 0; t < T_; ++t)
      qlstm_step<ushortT, true, true, NG><<<dim3(256), dim3(256), 0, stream>>>(
          outp, h0, c0, cbuf, bth_hi, bth_lo, xp, qx, Wfp, bfp, qa, qb, qp, t);
  } else if (ws_size >= t3){
    ushortT* xp     = (ushortT*)ws;
    ushortT* btx    = (ushortT*)(ws + XPF);          // btx region doubles as cbuf
    ushortT* bth_hi = (ushortT*)(ws + XPF + WB);
    float*   cbuf   = (float*)btx;                   // btx dead after xproj; safe overlap
    prep_w<<<dim3(3088), dim3(256), 0, stream>>>(Wi, Wg, Wo, Wf, btx, bth_hi, bth_hi, 0);
    xproj_gemm<ushortT, false, NTOT><<<dim3(13, 512), dim3(256), 0, stream>>>(
        x, btx, bi, bg, bo, bfv, xp, nullptr);
    for (int t = 0; t < T_; ++t)
      qlstm_step<ushortT, false, false, NTOT><<<dim3(256), dim3(256), 0, stream>>>(
          outp, h0, c0, cbuf, bth_hi, bth_hi, xp, nullptr, Wfp, bfp, qa, qb, qp, t);
  }
  // else: ws too small — leave out zeroed (fail loud with absmax = max|ref|)
}